// Round 11
// baseline (99.988 us; speedup 1.0000x reference)
//
#include <hip/hip_runtime.h>
#include <hip/hip_bf16.h>

#define NN 8192
#define F 64
#define ALPHA 0.2f
#define L2E 1.44269504f
#define DBOUND 16.0f
#define G 8
#define COLS (NN / G)        // 1024
#define NSTEPS (COLS / 32)   // 32
#define NCHUNK 4             // 8 steps (256 cols) per chunk

typedef __attribute__((ext_vector_type(8))) short short8;
typedef __attribute__((ext_vector_type(4))) float f32x4;
typedef __attribute__((ext_vector_type(4))) int i32x4;

__device__ __forceinline__ unsigned fb(float x) {
    return __builtin_bit_cast(unsigned, x);
}
__device__ __forceinline__ short f2bf(float x) {
    union { float f; unsigned u; } v; v.f = x;
    unsigned r = v.u + 0x7FFF + ((v.u >> 16) & 1);
    return (short)(r >> 16);
}

// Kernel A: Wh = h @ W^T (fp32), store WhT (bf16, transposed 64 x 8192),
// src = Wh@a1 (raw), dst2 = (Wh@a2) * log2(e).
__global__ __launch_bounds__(256) void k_prep(const float* __restrict__ h,
        const float* __restrict__ W, const float* __restrict__ a,
        short* __restrict__ WhT, float* __restrict__ src, float* __restrict__ dst2) {
    __shared__ float Wl[F][F + 1];
    __shared__ short shT[F][4];
    int tid = threadIdx.x;
    for (int m = 0; m < 4; ++m) {
        int idx = m * 1024 + tid * 4;
        float4 v = *(const float4*)&W[idx];
        int row = idx >> 6, col = idx & 63;
        Wl[row][col] = v.x; Wl[row][col + 1] = v.y;
        Wl[row][col + 2] = v.z; Wl[row][col + 3] = v.w;
    }
    __syncthreads();
    int w = tid >> 6, lane = tid & 63;
    int i = blockIdx.x * 4 + w;
    const float* hrow = &h[(size_t)i * F];
    float wh = 0.f;
    #pragma unroll
    for (int k = 0; k < F; k += 4) {
        float4 hv = *(const float4*)&hrow[k];
        wh += hv.x * Wl[lane][k] + hv.y * Wl[lane][k + 1]
            + hv.z * Wl[lane][k + 2] + hv.w * Wl[lane][k + 3];
    }
    shT[lane][w] = f2bf(wh);
    float s1 = wh * a[lane];
    float s2 = wh * a[F + lane];
    #pragma unroll
    for (int off = 32; off; off >>= 1) {
        s1 += __shfl_xor(s1, off);
        s2 += __shfl_xor(s2, off);
    }
    if (lane == 0) { src[i] = s1; dst2[i] = s2 * L2E; }
    __syncthreads();
    if (tid < F) {
        short4 v = make_short4(shT[tid][0], shT[tid][1], shT[tid][2], shT[tid][3]);
        *(short4*)&WhT[(size_t)tid * NN + blockIdx.x * 4] = v;
    }
}

// Kernel P: repack WhT [64][8192] into MFMA-fragment order.
__global__ __launch_bounds__(256) void k_pack(const short* __restrict__ WhT,
                                              short* __restrict__ WhTt) {
    int tid = blockIdx.x * 256 + threadIdx.x;   // 65536 threads
    int lp = tid & 63;
    int f  = (tid >> 6) & 3;
    int t  = tid >> 8;
    int row = f * 16 + (lp & 15);
    int col = t * 32 + ((lp >> 4) << 3);
    short8 v = *(const short8*)&WhT[(size_t)row * NN + col];
    *(short8*)&WhTt[(size_t)tid * 8] = v;
}

// Kernel B: FULLY FUSED masked-softmax attention. adj -> mask bits staged
// in-kernel (wave-linear 1KB NT loads, one row per wave-inst, shfl-or pack),
// double-buffered per 8-step chunk so adj HBM streaming overlaps compute.
// B-fragments direct from L2 (fragment-order WhTt), register double-buffered.
// One barrier per chunk.
__global__ __launch_bounds__(256, 4) void k_attn(const int* __restrict__ adj,
        const short8* __restrict__ WhTt, const float* __restrict__ src,
        const float* __restrict__ dst2,
        float* __restrict__ Opart, float* __restrict__ lpart) {
    __shared__ unsigned mlds[2][64][9];   // [buf][row][dword] (+pad col)
    __shared__ float dlds[COLS];          // dst2 slice

    int rb = blockIdx.x / G;
    int g  = blockIdx.x % G;
    int jbase = g * COLS;
    int tid = threadIdx.x;
    int w = tid >> 6, lane = tid & 63;

    for (int idx = tid; idx < COLS; idx += 256)
        dlds[idx] = dst2[jbase + idx];

    const int* abase = adj + (size_t)(rb * 64) * NN + jbase;
    int sh8 = 4 * (lane & 7);

    // Stage mask chunk c (cols c*256..+255, 64 rows) into mlds[c&1].
    // Wave w covers rows w, w+4, ..., w+60; one contiguous 1KB load per row.
#define STG1(rr, c, buf) { \
    i32x4 av = __builtin_nontemporal_load( \
        (const i32x4*)(abase + (size_t)(rr) * NN + (c) * 256) + lane); \
    unsigned n = (av.x > 0 ? 1u : 0u) | (av.y > 0 ? 2u : 0u) \
               | (av.z > 0 ? 4u : 0u) | (av.w > 0 ? 8u : 0u); \
    unsigned v = n << sh8; \
    v |= __shfl_xor(v, 1); v |= __shfl_xor(v, 2); v |= __shfl_xor(v, 4); \
    if ((lane & 7) == 0) mlds[buf][rr][lane >> 3] = v; }

#define STAGE(c) { int _b = (c) & 1; \
    STG1(w,      c, _b) STG1(w + 4,  c, _b) STG1(w + 8,  c, _b) STG1(w + 12, c, _b) \
    STG1(w + 16, c, _b) STG1(w + 20, c, _b) STG1(w + 24, c, _b) STG1(w + 28, c, _b) \
    STG1(w + 32, c, _b) STG1(w + 36, c, _b) STG1(w + 40, c, _b) STG1(w + 44, c, _b) \
    STG1(w + 48, c, _b) STG1(w + 52, c, _b) STG1(w + 56, c, _b) STG1(w + 60, c, _b) }

    int r = lane & 15, q = lane >> 4;
    int qs = q * 8;
    int i = rb * 64 + w * 16 + r;

    float srcv = src[i];
    float sM = srcv + DBOUND;
    float Mi = fmaxf(sM, ALPHA * sM);
    float sL  = srcv * L2E;
    float MiL = Mi * L2E;
    float C1 = sL - MiL;
    float C2 = fmaf(sL, ALPHA, -MiL);

    f32x4 acc0{}, acc1{}, acc2{}, acc3{}, acc4{};
    short8 ones;
    #pragma unroll
    for (int k = 0; k < 8; ++k) ones[k] = (short)0x3F80;  // bf16 1.0

#define LDB(tt, B0, B1, B2, B3) { \
    const short8* bp = WhTt + (size_t)(g * 32 + (tt)) * 256; \
    B0 = bp[lane]; B1 = bp[64 + lane]; B2 = bp[128 + lane]; B3 = bp[192 + lane]; }

#define PEL(dv, bit, eo) { \
    float t1 = (dv) + C1; \
    float t2 = fmaf((dv), ALPHA, C2); \
    float e = __builtin_amdgcn_exp2f(fmaxf(t1, t2)); \
    eo = (bit) ? e : 0.0f; }

    short8 cb0, cb1, cb2, cb3, nb0, nb1, nb2, nb3;
    LDB(0, cb0, cb1, cb2, cb3)
    STAGE(0)
    __syncthreads();

    for (int c = 0; c < NCHUNK; ++c) {
        if (c + 1 < NCHUNK) STAGE(c + 1)          // writes mlds[(c+1)&1]

        #pragma unroll
        for (int ts = 0; ts < 8; ++ts) {
            int t = c * 8 + ts;
            int tn = (t + 1 < NSTEPS) ? t + 1 : t;
            LDB(tn, nb0, nb1, nb2, nb3)           // in flight over this step

            unsigned m8 = (mlds[c & 1][w * 16 + r][ts] >> qs) & 0xffu;
            float4 d0 = *(const float4*)&dlds[t * 32 + qs];
            float4 d1 = *(const float4*)&dlds[t * 32 + qs + 4];

            float e0, e1, e2, e3, e4, e5, e6, e7;
            PEL(d0.x, (m8 & 1u),   e0) PEL(d0.y, (m8 & 2u),   e1)
            PEL(d0.z, (m8 & 4u),   e2) PEL(d0.w, (m8 & 8u),   e3)
            PEL(d1.x, (m8 & 16u),  e4) PEL(d1.y, (m8 & 32u),  e5)
            PEL(d1.z, (m8 & 64u),  e6) PEL(d1.w, (m8 & 128u), e7)

            unsigned w0 = __builtin_amdgcn_perm(fb(e1), fb(e0), 0x07060302u);
            unsigned w1 = __builtin_amdgcn_perm(fb(e3), fb(e2), 0x07060302u);
            unsigned w2 = __builtin_amdgcn_perm(fb(e5), fb(e4), 0x07060302u);
            unsigned w3 = __builtin_amdgcn_perm(fb(e7), fb(e6), 0x07060302u);
            short8 af = __builtin_bit_cast(short8, make_uint4(w0, w1, w2, w3));

            acc0 = __builtin_amdgcn_mfma_f32_16x16x32_bf16(af, cb0, acc0, 0, 0, 0);
            acc1 = __builtin_amdgcn_mfma_f32_16x16x32_bf16(af, cb1, acc1, 0, 0, 0);
            acc2 = __builtin_amdgcn_mfma_f32_16x16x32_bf16(af, cb2, acc2, 0, 0, 0);
            acc3 = __builtin_amdgcn_mfma_f32_16x16x32_bf16(af, cb3, acc3, 0, 0, 0);
            acc4 = __builtin_amdgcn_mfma_f32_16x16x32_bf16(af, ones, acc4, 0, 0, 0);

            cb0 = nb0; cb1 = nb1; cb2 = nb2; cb3 = nb3;
        }
        __syncthreads();                          // mlds[c&1] free; (c+1)&1 ready
    }
#undef PEL
#undef LDB
#undef STAGE
#undef STG1

    // acc4: every column holds the row-sum; C rows = q*4 + reg.
    int ic = rb * 64 + w * 16 + q * 4;
    if (r == 0) {
        #pragma unroll
        for (int reg = 0; reg < 4; ++reg)
            lpart[(size_t)g * NN + ic + reg] = acc4[reg];
    }

    size_t ob = (size_t)g * (size_t)(NN * F);
    #pragma unroll
    for (int reg = 0; reg < 4; ++reg) {
        size_t ro = ob + (size_t)(ic + reg) * F + r;
        Opart[ro]      = acc0[reg];
        Opart[ro + 16] = acc1[reg];
        Opart[ro + 32] = acc2[reg];
        Opart[ro + 48] = acc3[reg];
    }
}

// Kernel D: out = elu( (sum_g Opart) / (sum_g lpart) )
__global__ __launch_bounds__(256) void k_reduce(const float* __restrict__ Opart,
        const float* __restrict__ lpart, float* __restrict__ out) {
    int idx = blockIdx.x * 256 + threadIdx.x;
    int i = idx >> 6;
    float o = 0.f, l = 0.f;
    #pragma unroll
    for (int g = 0; g < G; ++g) {
        o += Opart[(size_t)g * (NN * F) + idx];
        l += lpart[(size_t)g * NN + i];
    }
    float hp = o / l;
    out[idx] = hp > 0.f ? hp : __expf(hp) - 1.f;
}

extern "C" void kernel_launch(void* const* d_in, const int* in_sizes, int n_in,
                              void* d_out, int out_size, void* d_ws, size_t ws_size,
                              hipStream_t stream) {
    const float* h  = (const float*)d_in[0];
    const int* adj  = (const int*)d_in[1];
    const float* W  = (const float*)d_in[2];
    const float* a  = (const float*)d_in[3];
    float* out = (float*)d_out;

    char* ws = (char*)d_ws;
    const size_t OFF_WHT  = 0;                       // 1 MB bf16 WhT
    const size_t OFF_WHTT = (1u << 20);              // 1 MB fragment-order WhTt
    const size_t OFF_SRC  = (2u << 20);              // 32 KB
    const size_t OFF_DST  = OFF_SRC + (32u << 10);   // 32 KB
    const size_t OFF_LP   = OFF_DST + (32u << 10);   // 256 KB (G*NN*4)
    const size_t OFF_OP   = OFF_LP + (size_t)G * NN * 4;      // 16 MB Opart

    short* WhT   = (short*)(ws + OFF_WHT);
    short* WhTt  = (short*)(ws + OFF_WHTT);
    float* src   = (float*)(ws + OFF_SRC);
    float* dst2  = (float*)(ws + OFF_DST);
    float* lpart = (float*)(ws + OFF_LP);
    float* Opart = (float*)(ws + OFF_OP);

    k_prep<<<NN / 4, 256, 0, stream>>>(h, W, a, WhT, src, dst2);
    k_pack<<<256, 256, 0, stream>>>(WhT, WhTt);
    k_attn<<<(NN / 64) * G, 256, 0, stream>>>(adj, (const short8*)WhTt, src, dst2,
                                              Opart, lpart);
    k_reduce<<<(NN * F) / 256, 256, 0, stream>>>(Opart, lpart, out);
}